// Round 3
// baseline (180.313 us; speedup 1.0000x reference)
//
#include <hip/hip_runtime.h>

typedef __attribute__((ext_vector_type(8))) short short8;
typedef __attribute__((ext_vector_type(4))) float f32x4;
typedef unsigned short u16;

__device__ __forceinline__ u16 f2bf(float f) {
    unsigned u = __builtin_bit_cast(unsigned, f);
    u += 0x7fffu + ((u >> 16) & 1u);
    return (u16)(u >> 16);
}
__device__ __forceinline__ float bf2f(u16 h) {
    return __builtin_bit_cast(float, (unsigned)h << 16);
}

// async global->LDS, 16B per lane; LDS dest = wave-uniform base + lane*16
#define GLDS(G, LBYTE)                                                         \
    __builtin_amdgcn_global_load_lds(                                          \
        (const __attribute__((address_space(1))) void*)(G),                    \
        (__attribute__((address_space(3))) void*)((char*)lds + (LBYTE)),       \
        16, 0, 0)

// NT GEMM: C[m,n] = sum_k A[m,k]*B[n,k]  (A:[M,K] bf16(+lo), B:[N,K] bf16(+lo))
// 128x64 tile, BK=32, 256 threads = 4 waves (2x2 of 64x32 each, acc 4x2).
// SPLIT: A,B given as hi+lo bf16 planes, 3 MFMAs (hi*hi + hi*lo + lo*hi).
// OUT: 0 = fp32, 1 = bf16, 2 = bf16 hi+lo pair (Cv=hi plane, C2=lo plane).
template<bool SPLIT, int OUT, bool BIAS, bool RELU>
__global__ __launch_bounds__(256, 3)
void gemm_nt(const u16* __restrict__ Ah, const u16* __restrict__ Al,
             const u16* __restrict__ Bh, const u16* __restrict__ Bl,
             const float* __restrict__ bias,
             void* __restrict__ Cv, u16* __restrict__ C2,
             int K, int lda, int ldb, int ldc,
             long sA, long sB, long sC)
{
    // u16 layout: Ah [0,4096) | Bh [4096,6144) | Al [6144,10240) | Bl [10240,12288)
    __shared__ u16 lds[SPLIT ? 12288 : 6144];
    const int tid  = threadIdx.x;
    const int lane = tid & 63;
    const int wid  = tid >> 6;
    const int z  = blockIdx.z;
    const int m0 = blockIdx.y * 128;
    const int n0 = blockIdx.x * 64;

    // staging map: thread t -> row t>>2 (+64 for 2nd A chunk), col (t&3)*8
    const size_t srow = (size_t)(tid >> 2);
    const int    scol = (tid & 3) * 8;
    const unsigned ldsW = (unsigned)wid * 1024u;   // per-wave 1KB within 4KB chunk

    const u16* aH = Ah + (size_t)z * sA + ((size_t)m0 + srow) * lda + scol;
    const u16* bH = Bh + (size_t)z * sB + ((size_t)n0 + srow) * ldb + scol;
    const u16* aL = SPLIT ? (Al + (size_t)z * sA + ((size_t)m0 + srow) * lda + scol) : nullptr;
    const u16* bL = SPLIT ? (Bl + (size_t)z * sB + ((size_t)n0 + srow) * ldb + scol) : nullptr;

    const int wm  = (wid & 1) * 64;       // wave row in tile
    const int wn  = (wid >> 1) * 32;      // wave col in tile
    const int fr  = lane & 15;
    const int fco = (lane >> 4) * 8;

    f32x4 acc[4][2] = {};

    for (int k0 = 0; k0 < K; k0 += 32) {
        GLDS(aH + k0,                 0 + ldsW);
        GLDS(aH + k0 + 64 * lda,   4096 + ldsW);
        GLDS(bH + k0,              8192 + ldsW);
        if (SPLIT) {
            GLDS(aL + k0,             12288 + ldsW);
            GLDS(aL + k0 + 64 * lda,  16384 + ldsW);
            GLDS(bL + k0,             20480 + ldsW);
        }
        __syncthreads();

        short8 vah[4], vbh[2];
#pragma unroll
        for (int i = 0; i < 4; ++i)
            vah[i] = *(const short8*)(lds +        (wm + i * 16 + fr) * 32 + fco);
#pragma unroll
        for (int j = 0; j < 2; ++j)
            vbh[j] = *(const short8*)(lds + 4096 + (wn + j * 16 + fr) * 32 + fco);
#pragma unroll
        for (int i = 0; i < 4; ++i)
#pragma unroll
            for (int j = 0; j < 2; ++j)
                acc[i][j] = __builtin_amdgcn_mfma_f32_16x16x32_bf16(vah[i], vbh[j], acc[i][j], 0, 0, 0);

        if (SPLIT) {
            short8 val[4], vbl[2];
#pragma unroll
            for (int i = 0; i < 4; ++i)
                val[i] = *(const short8*)(lds +  6144 + (wm + i * 16 + fr) * 32 + fco);
#pragma unroll
            for (int j = 0; j < 2; ++j)
                vbl[j] = *(const short8*)(lds + 10240 + (wn + j * 16 + fr) * 32 + fco);
#pragma unroll
            for (int i = 0; i < 4; ++i)
#pragma unroll
                for (int j = 0; j < 2; ++j) {
                    acc[i][j] = __builtin_amdgcn_mfma_f32_16x16x32_bf16(vah[i], vbl[j], acc[i][j], 0, 0, 0);
                    acc[i][j] = __builtin_amdgcn_mfma_f32_16x16x32_bf16(val[i], vbh[j], acc[i][j], 0, 0, 0);
                }
        }
        __syncthreads();
    }

    float bj[2];
    if (BIAS) {
#pragma unroll
        for (int j = 0; j < 2; ++j) bj[j] = bias[n0 + wn + j * 16 + fr];
    }
    const long crow0 = m0 + wm + (lane >> 4) * 4;
    const long ccol0 = n0 + wn + fr;
    float* Cf = (float*)Cv + (size_t)z * sC;
    u16*   Cb = (u16*)Cv   + (size_t)z * sC;
    u16*   Cl = (OUT == 2) ? (C2 + (size_t)z * sC) : nullptr;
#pragma unroll
    for (int i = 0; i < 4; ++i)
#pragma unroll
        for (int j = 0; j < 2; ++j)
#pragma unroll
            for (int r = 0; r < 4; ++r) {
                float v = acc[i][j][r];
                if (BIAS) v += bj[j];
                if (RELU) v = fmaxf(v, 0.0f);
                const size_t idx = (size_t)(crow0 + i * 16 + r) * ldc + ccol0 + j * 16;
                if (OUT == 0) Cf[idx] = v;
                else if (OUT == 1) Cb[idx] = f2bf(v);
                else {
                    u16 h = f2bf(v);
                    Cb[idx] = h;
                    Cl[idx] = f2bf(v - bf2f(h));
                }
            }
}

// fp32 -> (hi bf16, lo bf16) planes, vectorized
__global__ __launch_bounds__(256)
void split_f32(const float* __restrict__ x, u16* __restrict__ hi,
               u16* __restrict__ lo, int n4)
{
    int i = blockIdx.x * 256 + threadIdx.x;
    const int stride = gridDim.x * 256;
    for (; i < n4; i += stride) {
        float4 v = ((const float4*)x)[i];
        ushort4 h, l;
        h.x = f2bf(v.x); l.x = f2bf(v.x - bf2f(h.x));
        h.y = f2bf(v.y); l.y = f2bf(v.y - bf2f(h.y));
        h.z = f2bf(v.z); l.z = f2bf(v.z - bf2f(h.z));
        h.w = f2bf(v.w); l.w = f2bf(v.w - bf2f(h.w));
        ((ushort4*)hi)[i] = h;
        ((ushort4*)lo)[i] = l;
    }
}

// per-batch transpose [512,768] fp32 -> [768,512] bf16
__global__ __launch_bounds__(256)
void transpose_to_bf16(const float* __restrict__ src, u16* __restrict__ dst)
{
    __shared__ u16 t[32][33];
    const int z = blockIdx.z;
    src += (size_t)z * 512 * 768;
    dst += (size_t)z * 768 * 512;
    const int h0 = blockIdx.x * 32;
    const int q0 = blockIdx.y * 32;
    const int tx = threadIdx.x;   // 0..31
    const int ty = threadIdx.y;   // 0..7
#pragma unroll
    for (int r = 0; r < 4; ++r)
        t[ty * 4 + r][tx] = f2bf(src[(size_t)(q0 + ty * 4 + r) * 768 + h0 + tx]);
    __syncthreads();
#pragma unroll
    for (int r = 0; r < 4; ++r)
        dst[(size_t)(h0 + ty * 4 + r) * 512 + q0 + tx] = t[tx][ty * 4 + r];
}

// MedLane masked softmax over 512 (fp32 in), writes bf16 probs in place
// (row stride stays 512 floats = 1024 bf16 elements)
__global__ __launch_bounds__(256)
void softmax_kernel(float* __restrict__ att, const int* __restrict__ seq_len)
{
    const int row = blockIdx.x;
    const int b   = row >> 9;
    float* s = att + (size_t)row * 512;
    const int L = seq_len[b];
    const int tid = threadIdx.x;

    __shared__ float red[4];

    const float v0 = s[tid];
    const float v1 = s[tid + 256];
    const float s0 = (tid < L) ? v0 : 0.0f;
    const float s1 = (tid + 256 < L) ? v1 : 0.0f;

    float m = fmaxf(s0, s1);
#pragma unroll
    for (int o = 32; o > 0; o >>= 1) m = fmaxf(m, __shfl_down(m, o));
    if ((tid & 63) == 0) red[tid >> 6] = m;
    __syncthreads();
    const float M = fmaxf(fmaxf(red[0], red[1]), fmaxf(red[2], red[3]));
    __syncthreads();

    const float e0 = expf(s0 - M);
    const float e1 = expf(s1 - M);

    float zs = e0 + e1;
#pragma unroll
    for (int o = 32; o > 0; o >>= 1) zs += __shfl_down(zs, o);
    if ((tid & 63) == 0) red[tid >> 6] = zs;
    __syncthreads();
    const float Z = red[0] + red[1] + red[2] + red[3];
    __syncthreads();

    const float p0 = (tid < L)       ? e0 / Z : 0.0f;
    const float p1 = (tid + 256 < L) ? e1 / Z : 0.0f;

    float ss = p0 + p1;
#pragma unroll
    for (int o = 32; o > 0; o >>= 1) ss += __shfl_down(ss, o);
    if ((tid & 63) == 0) red[tid >> 6] = ss;
    __syncthreads();
    const float S = red[0] + red[1] + red[2] + red[3];

    const float inv = 1.0f / (S + 1e-13f);
    u16* o16 = (u16*)s;
    o16[tid]       = f2bf(p0 * inv);
    o16[tid + 256] = f2bf(p1 * inv);
}

extern "C" void kernel_launch(void* const* d_in, const int* in_sizes, int n_in,
                              void* d_out, int out_size, void* d_ws, size_t ws_size,
                              hipStream_t stream)
{
    (void)in_sizes; (void)n_in; (void)out_size; (void)ws_size;
    constexpr int B = 16, L = 512, H = 768;
    constexpr size_t NPQ = (size_t)B * L * H;   // 6291456
    constexpr size_t NW  = (size_t)H * H;       // 589824

    const float* proj_p  = (const float*)d_in[0];
    const float* proj_q  = (const float*)d_in[1];
    const int*   seq_len = (const int*)d_in[2];
    const float* W       = (const float*)d_in[3];
    const float* bias    = (const float*)d_in[4];
    float* out = (float*)d_out;

    // workspace (u16 elements)
    u16* ws   = (u16*)d_ws;
    u16* Ah   = ws;                 // pq split, then pp split; later att_vec bf16
    u16* Al   = Ah + NPQ;
    u16* Wh   = Al + NPQ;
    u16* Wl   = Wh + NW;
    u16* pqT  = Wl + NW;            // [B,768,512] bf16
    float* att = (float*)(pqT + NPQ);  // [B,512,512] fp32 -> probs bf16 in place
    u16* att_vec = Ah;              // alias (pp split dead after GEMM2)

    // trans_q hi/lo planes live in d_out (exactly fills it), dead before GEMM5 writes
    u16* tq_hi = (u16*)d_out;
    u16* tq_lo = tq_hi + NPQ;

    // 1) splits + transposed bf16 proj_q
    split_f32<<<576, 256, 0, stream>>>(W, Wh, Wl, (int)(NW / 4));
    split_f32<<<2048, 256, 0, stream>>>(proj_q, Ah, Al, (int)(NPQ / 4));
    transpose_to_bf16<<<dim3(24, 16, 16), dim3(32, 8), 0, stream>>>(proj_q, pqT);

    // 2) trans_q = pq @ W^T + bias  (split in, split out)
    gemm_nt<true, 2, true, false><<<dim3(12, 64, 1), 256, 0, stream>>>(
        Ah, Al, Wh, Wl, bias, tq_hi, tq_lo, H, H, H, H, 0, 0, 0);

    // 3) pp split (reuse Ah/Al)
    split_f32<<<2048, 256, 0, stream>>>(proj_p, Ah, Al, (int)(NPQ / 4));

    // 4) att[b] = pp[b] @ trans_q[b]^T  (split in, fp32 out)
    gemm_nt<true, 0, false, false><<<dim3(8, 4, 16), 256, 0, stream>>>(
        Ah, Al, tq_hi, tq_lo, nullptr, att, nullptr, H, H, H, L,
        (long)L * H, (long)L * H, (long)L * L);

    // 5) masked softmax, bf16 probs in place (lda = 1024 u16)
    softmax_kernel<<<B * L, 256, 0, stream>>>(att, seq_len);

    // 6) att_vec[b] = probs[b] @ pqT[b]^T  (bf16, bf16 out)
    gemm_nt<false, 1, false, false><<<dim3(12, 4, 16), 256, 0, stream>>>(
        (const u16*)att, nullptr, pqT, nullptr, nullptr, att_vec, nullptr,
        L, 1024, L, H, (long)L * 1024, (long)H * L, (long)L * H);

    // 7) out = relu(att_vec @ W^T + bias)  (bf16 in, fp32 out)
    gemm_nt<false, 0, true, true><<<dim3(12, 64, 1), 256, 0, stream>>>(
        att_vec, nullptr, Wh, nullptr, bias, out, nullptr, H, H, H, H, 0, 0, 0);
}

// Round 4
// 162.279 us; speedup vs baseline: 1.1111x; 1.1111x over previous
//
#include <hip/hip_runtime.h>

typedef __attribute__((ext_vector_type(8))) short short8;
typedef __attribute__((ext_vector_type(4))) float f32x4;
typedef unsigned short u16;

__device__ __forceinline__ u16 f2bf(float f) {
    unsigned u = __builtin_bit_cast(unsigned, f);
    u += 0x7fffu + ((u >> 16) & 1u);
    return (u16)(u >> 16);
}
__device__ __forceinline__ float bf2f(u16 h) {
    return __builtin_bit_cast(float, (unsigned)h << 16);
}

// async global->LDS, 16B per lane; LDS dest = wave-uniform base + lane*16
#define GLDS(G, LBYTE)                                                         \
    __builtin_amdgcn_global_load_lds(                                          \
        (const __attribute__((address_space(1))) void*)(G),                    \
        (__attribute__((address_space(3))) void*)((char*)lds + (LBYTE)),       \
        16, 0, 0)

// NT GEMM: C[m,n] = sum_k A[m,k]*B[n,k]  (A:[M,K] bf16(+lo), B:[N,K] bf16(+lo))
// 128x64 tile, BK=64, 256 threads = 4 waves (2x2 of 64x32 each, acc 4x2).
// LDS: row pitch 128B (64 bf16), 8 slots of 16B, XOR-swizzled slot ^= row&7.
//   Staged via global_load_lds with PRE-SWIZZLED per-lane global source
//   (linear LDS dest), read back with the same XOR -> conflict-free.
// SPLIT: A,B given as hi+lo bf16 planes, 3 MFMAs (hi*hi + hi*lo + lo*hi).
// OUT: 0 = fp32, 1 = bf16, 2 = bf16 hi+lo pair (Cv=hi plane, C2=lo plane).
template<bool SPLIT, int OUT, bool BIAS, bool RELU>
__global__ __launch_bounds__(256, 3)
void gemm_nt(const u16* __restrict__ Ah, const u16* __restrict__ Al,
             const u16* __restrict__ Bh, const u16* __restrict__ Bl,
             const float* __restrict__ bias,
             void* __restrict__ Cv, u16* __restrict__ C2,
             int K, int lda, int ldb, int ldc,
             long sA, long sB, long sC)
{
    // u16 elem offsets: Ah 0 | Bh 8192 | Al 12288 | Bl 20480  (48KB split, 24KB not)
    __shared__ u16 lds[SPLIT ? 24576 : 12288];
    const int tid  = threadIdx.x;
    const int lane = tid & 63;
    const int wid  = tid >> 6;
    const int z  = blockIdx.z;
    const int m0 = blockIdx.y * 128;
    const int n0 = blockIdx.x * 64;

    // staging map: thread t -> chunk row t>>3 (32 rows/4KB chunk),
    // swizzled source col group (t&7)^(row&7), 8 bf16 elems each
    const int rowA = tid >> 3;                       // 0..31
    const int colp = ((tid & 7) ^ (rowA & 7)) * 8;   // pre-swizzled col (elems)
    const unsigned ldsW = (unsigned)wid * 1024u;     // per-wave 1KB within 4KB chunk

    const u16* aH = Ah + (size_t)z * sA + ((size_t)m0 + rowA) * lda + colp;
    const u16* bH = Bh + (size_t)z * sB + ((size_t)n0 + rowA) * ldb + colp;
    const u16* aL = SPLIT ? (Al + (size_t)z * sA + ((size_t)m0 + rowA) * lda + colp) : nullptr;
    const u16* bL = SPLIT ? (Bl + (size_t)z * sB + ((size_t)n0 + rowA) * ldb + colp) : nullptr;

    const int wm = (wid & 1) * 64;        // wave row in tile
    const int wn = (wid >> 1) * 32;       // wave col in tile
    const int fr = lane & 15;             // fragment row within 16
    const int fq = lane >> 4;             // fragment k-quad (0..3)
    const int rx = fr & 7;                // read-side XOR key

    f32x4 acc[4][2] = {};

    for (int k0 = 0; k0 < K; k0 += 64) {
        GLDS(aH + k0,                  0 + ldsW);
        GLDS(aH + k0 + 32 * lda,    4096 + ldsW);
        GLDS(aH + k0 + 64 * lda,    8192 + ldsW);
        GLDS(aH + k0 + 96 * lda,   12288 + ldsW);
        GLDS(bH + k0,              16384 + ldsW);
        GLDS(bH + k0 + 32 * ldb,   20480 + ldsW);
        if (SPLIT) {
            GLDS(aL + k0,              24576 + ldsW);
            GLDS(aL + k0 + 32 * lda,   28672 + ldsW);
            GLDS(aL + k0 + 64 * lda,   32768 + ldsW);
            GLDS(aL + k0 + 96 * lda,   36864 + ldsW);
            GLDS(bL + k0,              40960 + ldsW);
            GLDS(bL + k0 + 32 * ldb,   45056 + ldsW);
        }
        __syncthreads();

#pragma unroll
        for (int w = 0; w < 2; ++w) {
            const int sl = w << 2;  // slot-linear base for this K=32 window
            short8 vah[4], vbh[2];
#pragma unroll
            for (int i = 0; i < 4; ++i)
                vah[i] = *(const short8*)(lds +
                    (wm + i * 16 + fr) * 64 + (((sl | fq) ^ rx) << 3));
#pragma unroll
            for (int j = 0; j < 2; ++j)
                vbh[j] = *(const short8*)(lds + 8192 +
                    (wn + j * 16 + fr) * 64 + (((sl | fq) ^ rx) << 3));
#pragma unroll
            for (int i = 0; i < 4; ++i)
#pragma unroll
                for (int j = 0; j < 2; ++j)
                    acc[i][j] = __builtin_amdgcn_mfma_f32_16x16x32_bf16(vah[i], vbh[j], acc[i][j], 0, 0, 0);

            if (SPLIT) {
                short8 val[4], vbl[2];
#pragma unroll
                for (int i = 0; i < 4; ++i)
                    val[i] = *(const short8*)(lds + 12288 +
                        (wm + i * 16 + fr) * 64 + (((sl | fq) ^ rx) << 3));
#pragma unroll
                for (int j = 0; j < 2; ++j)
                    vbl[j] = *(const short8*)(lds + 20480 +
                        (wn + j * 16 + fr) * 64 + (((sl | fq) ^ rx) << 3));
#pragma unroll
                for (int i = 0; i < 4; ++i)
#pragma unroll
                    for (int j = 0; j < 2; ++j) {
                        acc[i][j] = __builtin_amdgcn_mfma_f32_16x16x32_bf16(vah[i], vbl[j], acc[i][j], 0, 0, 0);
                        acc[i][j] = __builtin_amdgcn_mfma_f32_16x16x32_bf16(val[i], vbh[j], acc[i][j], 0, 0, 0);
                    }
            }
        }
        __syncthreads();
    }

    float bj[2];
    if (BIAS) {
#pragma unroll
        for (int j = 0; j < 2; ++j) bj[j] = bias[n0 + wn + j * 16 + fr];
    }
    const long crow0 = m0 + wm + fq * 4;
    const long ccol0 = n0 + wn + fr;
    float* Cf = (float*)Cv + (size_t)z * sC;
    u16*   Cb = (u16*)Cv   + (size_t)z * sC;
    u16*   Cl = (OUT == 2) ? (C2 + (size_t)z * sC) : nullptr;
#pragma unroll
    for (int i = 0; i < 4; ++i)
#pragma unroll
        for (int j = 0; j < 2; ++j)
#pragma unroll
            for (int r = 0; r < 4; ++r) {
                float v = acc[i][j][r];
                if (BIAS) v += bj[j];
                if (RELU) v = fmaxf(v, 0.0f);
                const size_t idx = (size_t)(crow0 + i * 16 + r) * ldc + ccol0 + j * 16;
                if (OUT == 0) Cf[idx] = v;
                else if (OUT == 1) Cb[idx] = f2bf(v);
                else {
                    u16 h = f2bf(v);
                    Cb[idx] = h;
                    Cl[idx] = f2bf(v - bf2f(h));
                }
            }
}

// fp32 -> (hi bf16, lo bf16) planes, vectorized
__global__ __launch_bounds__(256)
void split_f32(const float* __restrict__ x, u16* __restrict__ hi,
               u16* __restrict__ lo, int n4)
{
    int i = blockIdx.x * 256 + threadIdx.x;
    const int stride = gridDim.x * 256;
    for (; i < n4; i += stride) {
        float4 v = ((const float4*)x)[i];
        ushort4 h, l;
        h.x = f2bf(v.x); l.x = f2bf(v.x - bf2f(h.x));
        h.y = f2bf(v.y); l.y = f2bf(v.y - bf2f(h.y));
        h.z = f2bf(v.z); l.z = f2bf(v.z - bf2f(h.z));
        h.w = f2bf(v.w); l.w = f2bf(v.w - bf2f(h.w));
        ((ushort4*)hi)[i] = h;
        ((ushort4*)lo)[i] = l;
    }
}

// per-batch transpose [512,768] fp32 -> [768,512] bf16
__global__ __launch_bounds__(256)
void transpose_to_bf16(const float* __restrict__ src, u16* __restrict__ dst)
{
    __shared__ u16 t[32][33];
    const int z = blockIdx.z;
    src += (size_t)z * 512 * 768;
    dst += (size_t)z * 768 * 512;
    const int h0 = blockIdx.x * 32;
    const int q0 = blockIdx.y * 32;
    const int tx = threadIdx.x;   // 0..31
    const int ty = threadIdx.y;   // 0..7
#pragma unroll
    for (int r = 0; r < 4; ++r)
        t[ty * 4 + r][tx] = f2bf(src[(size_t)(q0 + ty * 4 + r) * 768 + h0 + tx]);
    __syncthreads();
#pragma unroll
    for (int r = 0; r < 4; ++r)
        dst[(size_t)(h0 + ty * 4 + r) * 512 + q0 + tx] = t[tx][ty * 4 + r];
}

// MedLane masked softmax over 512 (fp32 in), writes bf16 probs in place
// (row stride stays 512 floats = 1024 bf16 elements)
__global__ __launch_bounds__(256)
void softmax_kernel(float* __restrict__ att, const int* __restrict__ seq_len)
{
    const int row = blockIdx.x;
    const int b   = row >> 9;
    float* s = att + (size_t)row * 512;
    const int L = seq_len[b];
    const int tid = threadIdx.x;

    __shared__ float red[4];

    const float v0 = s[tid];
    const float v1 = s[tid + 256];
    const float s0 = (tid < L) ? v0 : 0.0f;
    const float s1 = (tid + 256 < L) ? v1 : 0.0f;

    float m = fmaxf(s0, s1);
#pragma unroll
    for (int o = 32; o > 0; o >>= 1) m = fmaxf(m, __shfl_down(m, o));
    if ((tid & 63) == 0) red[tid >> 6] = m;
    __syncthreads();
    const float M = fmaxf(fmaxf(red[0], red[1]), fmaxf(red[2], red[3]));
    __syncthreads();

    const float e0 = expf(s0 - M);
    const float e1 = expf(s1 - M);

    float zs = e0 + e1;
#pragma unroll
    for (int o = 32; o > 0; o >>= 1) zs += __shfl_down(zs, o);
    if ((tid & 63) == 0) red[tid >> 6] = zs;
    __syncthreads();
    const float Z = red[0] + red[1] + red[2] + red[3];
    __syncthreads();

    const float p0 = (tid < L)       ? e0 / Z : 0.0f;
    const float p1 = (tid + 256 < L) ? e1 / Z : 0.0f;

    float ss = p0 + p1;
#pragma unroll
    for (int o = 32; o > 0; o >>= 1) ss += __shfl_down(ss, o);
    if ((tid & 63) == 0) red[tid >> 6] = ss;
    __syncthreads();
    const float S = red[0] + red[1] + red[2] + red[3];

    const float inv = 1.0f / (S + 1e-13f);
    u16* o16 = (u16*)s;
    o16[tid]       = f2bf(p0 * inv);
    o16[tid + 256] = f2bf(p1 * inv);
}

extern "C" void kernel_launch(void* const* d_in, const int* in_sizes, int n_in,
                              void* d_out, int out_size, void* d_ws, size_t ws_size,
                              hipStream_t stream)
{
    (void)in_sizes; (void)n_in; (void)out_size; (void)ws_size;
    constexpr int B = 16, L = 512, H = 768;
    constexpr size_t NPQ = (size_t)B * L * H;   // 6291456
    constexpr size_t NW  = (size_t)H * H;       // 589824

    const float* proj_p  = (const float*)d_in[0];
    const float* proj_q  = (const float*)d_in[1];
    const int*   seq_len = (const int*)d_in[2];
    const float* W       = (const float*)d_in[3];
    const float* bias    = (const float*)d_in[4];
    float* out = (float*)d_out;

    // workspace (u16 elements)
    u16* ws   = (u16*)d_ws;
    u16* Ah   = ws;                 // pq split, then pp split; later att_vec bf16
    u16* Al   = Ah + NPQ;
    u16* Wh   = Al + NPQ;
    u16* Wl   = Wh + NW;
    u16* pqT  = Wl + NW;            // [B,768,512] bf16
    float* att = (float*)(pqT + NPQ);  // [B,512,512] fp32 -> probs bf16 in place
    u16* att_vec = Ah;              // alias (pp split dead after GEMM2)

    // trans_q hi/lo planes live in d_out (exactly fills it), dead before GEMM5 writes
    u16* tq_hi = (u16*)d_out;
    u16* tq_lo = tq_hi + NPQ;

    // 1) splits + transposed bf16 proj_q
    split_f32<<<576, 256, 0, stream>>>(W, Wh, Wl, (int)(NW / 4));
    split_f32<<<2048, 256, 0, stream>>>(proj_q, Ah, Al, (int)(NPQ / 4));
    transpose_to_bf16<<<dim3(24, 16, 16), dim3(32, 8), 0, stream>>>(proj_q, pqT);

    // 2) trans_q = pq @ W^T + bias  (split in, split out)
    gemm_nt<true, 2, true, false><<<dim3(12, 64, 1), 256, 0, stream>>>(
        Ah, Al, Wh, Wl, bias, tq_hi, tq_lo, H, H, H, H, 0, 0, 0);

    // 3) pp split (reuse Ah/Al)
    split_f32<<<2048, 256, 0, stream>>>(proj_p, Ah, Al, (int)(NPQ / 4));

    // 4) att[b] = pp[b] @ trans_q[b]^T  (split in, fp32 out)
    gemm_nt<true, 0, false, false><<<dim3(8, 4, 16), 256, 0, stream>>>(
        Ah, Al, tq_hi, tq_lo, nullptr, att, nullptr, H, H, H, L,
        (long)L * H, (long)L * H, (long)L * L);

    // 5) masked softmax, bf16 probs in place (lda = 1024 u16)
    softmax_kernel<<<B * L, 256, 0, stream>>>(att, seq_len);

    // 6) att_vec[b] = probs[b] @ pqT[b]^T  (bf16, bf16 out)
    gemm_nt<false, 1, false, false><<<dim3(12, 4, 16), 256, 0, stream>>>(
        (const u16*)att, nullptr, pqT, nullptr, nullptr, att_vec, nullptr,
        L, 1024, L, H, (long)L * 1024, (long)H * L, (long)L * H);

    // 7) out = relu(att_vec @ W^T + bias)  (bf16 in, fp32 out)
    gemm_nt<false, 0, true, true><<<dim3(12, 64, 1), 256, 0, stream>>>(
        att_vec, nullptr, Wh, nullptr, bias, out, nullptr, H, H, H, H, 0, 0, 0);
}

// Round 5
// 138.708 us; speedup vs baseline: 1.2999x; 1.1699x over previous
//
#include <hip/hip_runtime.h>

typedef __attribute__((ext_vector_type(8))) short short8;
typedef __attribute__((ext_vector_type(4))) float f32x4;
typedef unsigned short u16;

__device__ __forceinline__ u16 f2bf(float f) {
    unsigned u = __builtin_bit_cast(unsigned, f);
    u += 0x7fffu + ((u >> 16) & 1u);
    return (u16)(u >> 16);
}
__device__ __forceinline__ float bf2f(u16 h) {
    return __builtin_bit_cast(float, (unsigned)h << 16);
}

// async global->LDS, 16B per lane; LDS dest = wave-uniform base + lane*16
#define GLDS(G, LBYTE)                                                         \
    __builtin_amdgcn_global_load_lds(                                          \
        (const __attribute__((address_space(1))) void*)(G),                    \
        (__attribute__((address_space(3))) void*)((char*)lds + (LBYTE)),       \
        16, 0, 0)

// NT GEMM: C[m,n] = sum_k A[m,k]*B[n,k]  (A:[M,K] bf16(+lo), B:[N,K] bf16(+lo))
// 128x64 tile, 256 threads = 4 waves (2x2 of 64x32 each, acc 4x2).
// Double-buffered LDS 2-phase pipeline: STAGE(next) issued BEFORE compute(cur),
// one __syncthreads() per K-step (its vmcnt(0) drain lands after compute).
// SPLIT (hi+lo bf16, 3 MFMAs): BK=32, buf = 24KB {Ah 8K | Bh 4K | Al 8K | Bl 4K}.
// non-split: BK=64, buf = 24KB {Ah 16K | Bh 8K}. Both: 2 bufs = 48KB LDS.
// XOR-swizzled LDS slots (pre-swizzled global source, linear LDS dest).
// XCD-aware bijective block swizzle: 1D grid, contiguous chunk per XCD.
// OUT: 0 = fp32, 1 = bf16, 2 = bf16 hi+lo pair (Cv=hi plane, C2=lo plane).
template<bool SPLIT, int OUT, bool BIAS, bool RELU, int GX, int GY>
__global__ __launch_bounds__(256, 3)
void gemm_nt(const u16* __restrict__ Ah, const u16* __restrict__ Al,
             const u16* __restrict__ Bh, const u16* __restrict__ Bl,
             const float* __restrict__ bias,
             void* __restrict__ Cv, u16* __restrict__ C2,
             int K, int lda, int ldb, int ldc,
             long sA, long sB, long sC)
{
    __shared__ u16 lds[24576];   // 48KB = 2 buffers x 24KB (both variants)
    constexpr int BK   = SPLIT ? 32 : 64;     // K per step
    constexpr int PIT  = BK;                  // LDS row pitch (u16)
    constexpr int SWM  = BK / 8 - 1;          // slot-swizzle mask (3 or 7)
    constexpr int BOF  = SPLIT ? 4096 : 8192; // B section offset (u16)
    constexpr int ALO  = 6144;                // A-lo section (u16, split only)
    constexpr int BLO  = 10240;               // B-lo section (u16, split only)
    constexpr int BUFB = 24576;               // buffer stride (bytes)
    constexpr int BUFE = 12288;               // buffer stride (u16)

    // ---- XCD-aware bijective block swizzle (nwg % 8 == 0 for all our grids)
    const unsigned flat = blockIdx.x;
    const unsigned cpx  = gridDim.x >> 3;
    const unsigned id   = (flat & 7u) * cpx + (flat >> 3);
    const int bz  = (int)(id / (unsigned)(GX * GY));
    const int rem = (int)(id - (unsigned)bz * (GX * GY));
    const int by  = rem / GX;
    const int bx  = rem - by * GX;

    const int tid  = threadIdx.x;
    const int lane = tid & 63;
    const int wid  = tid >> 6;
    const int m0 = by * 128;
    const int n0 = bx * 64;

    // staging map (pre-swizzled global source, linear LDS dest)
    const int rowS = SPLIT ? (tid >> 2) : (tid >> 3);
    const int colS = SPLIT ? (((tid & 3) ^ (rowS & 3)) * 8)
                           : (((tid & 7) ^ (rowS & 7)) * 8);
    const unsigned ldsW = (unsigned)wid * 1024u;  // wave base within 4KB chunk

    const u16* aH = Ah + (size_t)bz * sA + ((size_t)m0 + rowS) * lda + colS;
    const u16* bH = Bh + (size_t)bz * sB + ((size_t)n0 + rowS) * ldb + colS;
    const u16* aL = SPLIT ? (Al + (size_t)bz * sA + ((size_t)m0 + rowS) * lda + colS) : nullptr;
    const u16* bL = SPLIT ? (Bl + (size_t)bz * sB + ((size_t)n0 + rowS) * ldb + colS) : nullptr;

    const int wm = (wid & 1) * 64;        // wave row in tile
    const int wn = (wid >> 1) * 32;       // wave col in tile
    const int fr = lane & 15;             // fragment row within 16
    const int fq = lane >> 4;             // fragment k-quad (0..3)

    f32x4 acc[4][2] = {};

    auto stage = [&](int bb, int k0) {
        if constexpr (SPLIT) {
            GLDS(aH + k0,            bb +     0 + ldsW);
            GLDS(aH + k0 + 64 * lda, bb +  4096 + ldsW);
            GLDS(bH + k0,            bb +  8192 + ldsW);
            GLDS(aL + k0,            bb + 12288 + ldsW);
            GLDS(aL + k0 + 64 * lda, bb + 16384 + ldsW);
            GLDS(bL + k0,            bb + 20480 + ldsW);
        } else {
            GLDS(aH + k0,            bb +     0 + ldsW);
            GLDS(aH + k0 + 32 * lda, bb +  4096 + ldsW);
            GLDS(aH + k0 + 64 * lda, bb +  8192 + ldsW);
            GLDS(aH + k0 + 96 * lda, bb + 12288 + ldsW);
            GLDS(bH + k0,            bb + 16384 + ldsW);
            GLDS(bH + k0 + 32 * ldb, bb + 20480 + ldsW);
        }
    };

    auto compute = [&](int be) {
        if constexpr (SPLIT) {
            const int sw = (fq ^ (fr & 3)) << 3;
            short8 vah[4], vbh[2];
#pragma unroll
            for (int i = 0; i < 4; ++i)
                vah[i] = *(const short8*)(lds + be + (wm + i * 16 + fr) * PIT + sw);
#pragma unroll
            for (int j = 0; j < 2; ++j)
                vbh[j] = *(const short8*)(lds + be + BOF + (wn + j * 16 + fr) * PIT + sw);
#pragma unroll
            for (int i = 0; i < 4; ++i)
#pragma unroll
                for (int j = 0; j < 2; ++j)
                    acc[i][j] = __builtin_amdgcn_mfma_f32_16x16x32_bf16(vah[i], vbh[j], acc[i][j], 0, 0, 0);
            short8 val[4], vbl[2];
#pragma unroll
            for (int i = 0; i < 4; ++i)
                val[i] = *(const short8*)(lds + be + ALO + (wm + i * 16 + fr) * PIT + sw);
#pragma unroll
            for (int j = 0; j < 2; ++j)
                vbl[j] = *(const short8*)(lds + be + BLO + (wn + j * 16 + fr) * PIT + sw);
#pragma unroll
            for (int i = 0; i < 4; ++i)
#pragma unroll
                for (int j = 0; j < 2; ++j) {
                    acc[i][j] = __builtin_amdgcn_mfma_f32_16x16x32_bf16(vah[i], vbl[j], acc[i][j], 0, 0, 0);
                    acc[i][j] = __builtin_amdgcn_mfma_f32_16x16x32_bf16(val[i], vbh[j], acc[i][j], 0, 0, 0);
                }
        } else {
#pragma unroll
            for (int w = 0; w < 2; ++w) {
                const int sw = (((w << 2) | fq) ^ (fr & 7)) << 3;
                short8 vah[4], vbh[2];
#pragma unroll
                for (int i = 0; i < 4; ++i)
                    vah[i] = *(const short8*)(lds + be + (wm + i * 16 + fr) * PIT + sw);
#pragma unroll
                for (int j = 0; j < 2; ++j)
                    vbh[j] = *(const short8*)(lds + be + BOF + (wn + j * 16 + fr) * PIT + sw);
#pragma unroll
                for (int i = 0; i < 4; ++i)
#pragma unroll
                    for (int j = 0; j < 2; ++j)
                        acc[i][j] = __builtin_amdgcn_mfma_f32_16x16x32_bf16(vah[i], vbh[j], acc[i][j], 0, 0, 0);
            }
        }
    };

    // ---- 2-phase pipelined K-loop (K is a multiple of 2*BK for all calls)
    stage(0, 0);
    __syncthreads();                       // vmcnt(0) drain: buf0 ready
    for (int k0 = 0; k0 < K; k0 += 2 * BK) {
        if (k0 + BK < K) stage(BUFB, k0 + BK);   // prefetch into buf1
        compute(0);                               // compute buf0
        __syncthreads();                          // buf1 ready; buf0 free
        if (k0 + 2 * BK < K) stage(0, k0 + 2 * BK);
        compute(BUFE);                            // compute buf1
        __syncthreads();
    }

    float bj[2];
    if (BIAS) {
#pragma unroll
        for (int j = 0; j < 2; ++j) bj[j] = bias[n0 + wn + j * 16 + fr];
    }
    const long crow0 = m0 + wm + fq * 4;
    const long ccol0 = n0 + wn + fr;
    float* Cf = (float*)Cv + (size_t)bz * sC;
    u16*   Cb = (u16*)Cv   + (size_t)bz * sC;
    u16*   Cl = (OUT == 2) ? (C2 + (size_t)bz * sC) : nullptr;
#pragma unroll
    for (int i = 0; i < 4; ++i)
#pragma unroll
        for (int j = 0; j < 2; ++j)
#pragma unroll
            for (int r = 0; r < 4; ++r) {
                float v = acc[i][j][r];
                if (BIAS) v += bj[j];
                if (RELU) v = fmaxf(v, 0.0f);
                const size_t idx = (size_t)(crow0 + i * 16 + r) * ldc + ccol0 + j * 16;
                if (OUT == 0) Cf[idx] = v;
                else if (OUT == 1) Cb[idx] = f2bf(v);
                else {
                    u16 h = f2bf(v);
                    Cb[idx] = h;
                    Cl[idx] = f2bf(v - bf2f(h));
                }
            }
}

// fp32 -> (hi bf16, lo bf16) planes, vectorized
__global__ __launch_bounds__(256)
void split_f32(const float* __restrict__ x, u16* __restrict__ hi,
               u16* __restrict__ lo, int n4)
{
    int i = blockIdx.x * 256 + threadIdx.x;
    const int stride = gridDim.x * 256;
    for (; i < n4; i += stride) {
        float4 v = ((const float4*)x)[i];
        ushort4 h, l;
        h.x = f2bf(v.x); l.x = f2bf(v.x - bf2f(h.x));
        h.y = f2bf(v.y); l.y = f2bf(v.y - bf2f(h.y));
        h.z = f2bf(v.z); l.z = f2bf(v.z - bf2f(h.z));
        h.w = f2bf(v.w); l.w = f2bf(v.w - bf2f(h.w));
        ((ushort4*)hi)[i] = h;
        ((ushort4*)lo)[i] = l;
    }
}

// per-batch transpose [512,768] fp32 -> [768,512] bf16
__global__ __launch_bounds__(256)
void transpose_to_bf16(const float* __restrict__ src, u16* __restrict__ dst)
{
    __shared__ u16 t[32][33];
    const int z = blockIdx.z;
    src += (size_t)z * 512 * 768;
    dst += (size_t)z * 768 * 512;
    const int h0 = blockIdx.x * 32;
    const int q0 = blockIdx.y * 32;
    const int tx = threadIdx.x;   // 0..31
    const int ty = threadIdx.y;   // 0..7
#pragma unroll
    for (int r = 0; r < 4; ++r)
        t[ty * 4 + r][tx] = f2bf(src[(size_t)(q0 + ty * 4 + r) * 768 + h0 + tx]);
    __syncthreads();
#pragma unroll
    for (int r = 0; r < 4; ++r)
        dst[(size_t)(h0 + ty * 4 + r) * 512 + q0 + tx] = t[tx][ty * 4 + r];
}

// MedLane masked softmax over 512 (fp32 in), writes bf16 probs in place
// (row stride stays 512 floats = 1024 bf16 elements)
__global__ __launch_bounds__(256)
void softmax_kernel(float* __restrict__ att, const int* __restrict__ seq_len)
{
    const int row = blockIdx.x;
    const int b   = row >> 9;
    float* s = att + (size_t)row * 512;
    const int L = seq_len[b];
    const int tid = threadIdx.x;

    __shared__ float red[4];

    const float v0 = s[tid];
    const float v1 = s[tid + 256];
    const float s0 = (tid < L) ? v0 : 0.0f;
    const float s1 = (tid + 256 < L) ? v1 : 0.0f;

    float m = fmaxf(s0, s1);
#pragma unroll
    for (int o = 32; o > 0; o >>= 1) m = fmaxf(m, __shfl_down(m, o));
    if ((tid & 63) == 0) red[tid >> 6] = m;
    __syncthreads();
    const float M = fmaxf(fmaxf(red[0], red[1]), fmaxf(red[2], red[3]));
    __syncthreads();

    const float e0 = expf(s0 - M);
    const float e1 = expf(s1 - M);

    float zs = e0 + e1;
#pragma unroll
    for (int o = 32; o > 0; o >>= 1) zs += __shfl_down(zs, o);
    if ((tid & 63) == 0) red[tid >> 6] = zs;
    __syncthreads();
    const float Z = red[0] + red[1] + red[2] + red[3];
    __syncthreads();

    const float p0 = (tid < L)       ? e0 / Z : 0.0f;
    const float p1 = (tid + 256 < L) ? e1 / Z : 0.0f;

    float ss = p0 + p1;
#pragma unroll
    for (int o = 32; o > 0; o >>= 1) ss += __shfl_down(ss, o);
    if ((tid & 63) == 0) red[tid >> 6] = ss;
    __syncthreads();
    const float S = red[0] + red[1] + red[2] + red[3];

    const float inv = 1.0f / (S + 1e-13f);
    u16* o16 = (u16*)s;
    o16[tid]       = f2bf(p0 * inv);
    o16[tid + 256] = f2bf(p1 * inv);
}

extern "C" void kernel_launch(void* const* d_in, const int* in_sizes, int n_in,
                              void* d_out, int out_size, void* d_ws, size_t ws_size,
                              hipStream_t stream)
{
    (void)in_sizes; (void)n_in; (void)out_size; (void)ws_size;
    constexpr int B = 16, L = 512, H = 768;
    constexpr size_t NPQ = (size_t)B * L * H;   // 6291456
    constexpr size_t NW  = (size_t)H * H;       // 589824

    const float* proj_p  = (const float*)d_in[0];
    const float* proj_q  = (const float*)d_in[1];
    const int*   seq_len = (const int*)d_in[2];
    const float* W       = (const float*)d_in[3];
    const float* bias    = (const float*)d_in[4];
    float* out = (float*)d_out;

    // workspace (u16 elements)
    u16* ws   = (u16*)d_ws;
    u16* Ah   = ws;                 // pq split, then pp split; later att_vec bf16
    u16* Al   = Ah + NPQ;
    u16* Wh   = Al + NPQ;
    u16* Wl   = Wh + NW;
    u16* pqT  = Wl + NW;            // [B,768,512] bf16
    float* att = (float*)(pqT + NPQ);  // [B,512,512] fp32 -> probs bf16 in place
    u16* att_vec = Ah;              // alias (pp split dead after GEMM2)

    // trans_q hi/lo planes live in d_out (exactly fills it), dead before GEMM5 writes
    u16* tq_hi = (u16*)d_out;
    u16* tq_lo = tq_hi + NPQ;

    // 1) splits + transposed bf16 proj_q
    split_f32<<<576, 256, 0, stream>>>(W, Wh, Wl, (int)(NW / 4));
    split_f32<<<2048, 256, 0, stream>>>(proj_q, Ah, Al, (int)(NPQ / 4));
    transpose_to_bf16<<<dim3(24, 16, 16), dim3(32, 8), 0, stream>>>(proj_q, pqT);

    // 2) trans_q = pq @ W^T + bias  (split in, split out)  grid 12x64 = 768
    gemm_nt<true, 2, true, false, 12, 64><<<768, 256, 0, stream>>>(
        Ah, Al, Wh, Wl, bias, tq_hi, tq_lo, H, H, H, H, 0, 0, 0);

    // 3) pp split (reuse Ah/Al)
    split_f32<<<2048, 256, 0, stream>>>(proj_p, Ah, Al, (int)(NPQ / 4));

    // 4) att[b] = pp[b] @ trans_q[b]^T  (split in, fp32 out)  grid 8x4x16 = 512
    gemm_nt<true, 0, false, false, 8, 4><<<512, 256, 0, stream>>>(
        Ah, Al, tq_hi, tq_lo, nullptr, att, nullptr, H, H, H, L,
        (long)L * H, (long)L * H, (long)L * L);

    // 5) masked softmax, bf16 probs in place (lda = 1024 u16)
    softmax_kernel<<<B * L, 256, 0, stream>>>(att, seq_len);

    // 6) att_vec[b] = probs[b] @ pqT[b]^T  (bf16, bf16 out)  grid 12x4x16 = 768
    gemm_nt<false, 1, false, false, 12, 4><<<768, 256, 0, stream>>>(
        (const u16*)att, nullptr, pqT, nullptr, nullptr, att_vec, nullptr,
        L, 1024, L, H, (long)L * 1024, (long)H * L, (long)L * H);

    // 7) out = relu(att_vec @ W^T + bias)  (bf16 in, fp32 out)  grid 12x64 = 768
    gemm_nt<false, 0, true, true, 12, 64><<<768, 256, 0, stream>>>(
        att_vec, nullptr, Wh, nullptr, bias, out, nullptr, H, H, H, H, 0, 0, 0);
}